// Round 10
// baseline (306.238 us; speedup 1.0000x reference)
//
#include <hip/hip_runtime.h>
#include <math.h>

// Round 14 (resubmit; R9 was a container-infra failure — no pytest/rocprof
// stages ran; kernel audited for deadlock/fault modes, none found):
// R13 landed (300us). This round: fuse prep_all + router_lds into ONE kernel
// (router blocks self-compute gate norms during staging -> no g_vnorm
// dependency; prep blocks backfill CUs), double-buffer the gate LDS
// (1 barrier/chunk). main8 / mid64 untouched (clean attribution).

typedef unsigned short u16;
typedef __attribute__((ext_vector_type(8))) short short8;
typedef __attribute__((ext_vector_type(4))) float floatx4;

#define DEV __device__ __forceinline__

DEV u16 f2b(float f) { unsigned int u; __builtin_memcpy(&u, &f, 4); u += 0x7fffu + ((u >> 16) & 1u); return (u16)(u >> 16); }
DEV float ldf(const float* __restrict__ p, long long i, long long n) { if (i < 0 || i >= n) i = 0; return p[i]; }

DEV void async_cp16(const void* g, void* l) {
  __builtin_amdgcn_global_load_lds(
      (const __attribute__((address_space(1))) unsigned int*)g,
      (__attribute__((address_space(3))) unsigned int*)l, 16, 0, 0);
}

struct Route { int e0, e1; float c0, c1; };

#define MAX_T 8192
#define MAX_K 2048
#define MAX_DOUT 2048
#define MAX_ER 256

__device__ Route g_route[MAX_T];
__device__ float g_mid[(size_t)MAX_T * MAX_ER];               // legacy path
__device__ __align__(16) u16 g_xb[(size_t)MAX_T * MAX_K];     // x bf16
__device__ __align__(16) u16 g_wb[(size_t)MAX_DOUT * MAX_K];  // base_W bf16
__device__ __align__(16) u16 g_ab[(size_t)MAX_ER * MAX_K];    // A bf16
__device__ __align__(16) u16 g_mw[(size_t)MAX_T * MAX_ER];    // weighted mid bf16
__device__ __align__(16) u16 g_w2[(size_t)MAX_DOUT * MAX_ER]; // B permuted bf16

// ---------------- Fused router + prep (one dispatch) ----------------
// Blocks [0, Rblk): router (4 tokens/block, LDS-staged gate, double-buffered,
//   self-computed gate norms). Blocks [Rblk, ...): W cvt / A cvt / W2 build.
__global__ __launch_bounds__(256) void router_prep(
    const float* __restrict__ x, long long nX,
    const float* __restrict__ gate_v, long long nG,
    const float* __restrict__ alphas, long long nAl,
    const int* __restrict__ topk_ptr, int has_topk,
    const float* __restrict__ W, long long nW,
    const float* __restrict__ A, long long nA,
    const float* __restrict__ Bw, long long nB,
    int T, int d, int d_out, int r, int E, int Er,
    int Rblk, int nWblk, int nAblk, int w2blk) {
  __shared__ __align__(16) float gls[2][4096];  // 2 x (16 experts x 256 f32)
  __shared__ float vns[16];
  int b = blockIdx.x;
  const int tid = threadIdx.x;

  if (b < Rblk) {
    const int w = tid >> 6, lane = tid & 63;
    const int t = b * 4 + w;
    const bool valid = (t < T && t < MAX_T);
    const long long xbase = (long long)t * d;
    const int nch = d >> 8;  // d % 256 == 0 guaranteed by launcher

    float dot[16], xx = 0.f, vvp[4] = {0.f, 0.f, 0.f, 0.f};
#pragma unroll
    for (int e = 0; e < 16; ++e) dot[e] = 0.f;

    // stage chunk 0 into buf 0 (+ vnorm accumulation)
#pragma unroll
    for (int i = 0; i < 4; ++i) {
      const int f = tid * 4 + i * 1024;  // e = (tid>>6)+4i, kk = f&255
      const int e = f >> 8, kk = f & 255;
      float4 g = (float4){0.f, 0.f, 0.f, 0.f};
      if (e < E) g = *(const float4*)(gate_v + (long long)e * d + kk);
      vvp[i] += g.x * g.x + g.y * g.y + g.z * g.z + g.w * g.w;
      *(float4*)&gls[0][f] = g;
    }
    __syncthreads();

    for (int j = 0; j < nch; ++j) {
      if (j + 1 < nch) {  // stage next chunk into the other buffer
        const int k1 = (j + 1) << 8;
#pragma unroll
        for (int i = 0; i < 4; ++i) {
          const int f = tid * 4 + i * 1024;
          const int e = f >> 8, kk = f & 255;
          float4 g = (float4){0.f, 0.f, 0.f, 0.f};
          if (e < E) g = *(const float4*)(gate_v + (long long)e * d + k1 + kk);
          vvp[i] += g.x * g.x + g.y * g.y + g.z * g.z + g.w * g.w;
          *(float4*)&gls[(j + 1) & 1][f] = g;
        }
      }
      // compute on current buffer
      const int k0 = j << 8;
      float4 xv = (float4){0.f, 0.f, 0.f, 0.f};
      if (valid) {
        xv = *(const float4*)(x + xbase + k0 + lane * 4);
        ushort4 ob; ob.x = f2b(xv.x); ob.y = f2b(xv.y); ob.z = f2b(xv.z); ob.w = f2b(xv.w);
        *(ushort4*)&g_xb[xbase + k0 + lane * 4] = ob;
      }
      xx += xv.x * xv.x + xv.y * xv.y + xv.z * xv.z + xv.w * xv.w;
      const float* gb = gls[j & 1];
#pragma unroll
      for (int e = 0; e < 16; ++e) {
        if (e < E) {
          const float4 g = *(const float4*)&gb[e * 256 + lane * 4];
          dot[e] += xv.x * g.x + xv.y * g.y + xv.z * g.z + xv.w * g.w;
        }
      }
      __syncthreads();
    }

    // gate norms: wave w holds experts {w, w+4, w+8, w+12}
#pragma unroll
    for (int m = 1; m < 64; m <<= 1)
#pragma unroll
      for (int i = 0; i < 4; ++i) vvp[i] += __shfl_xor(vvp[i], m);
    if (lane == 0) {
#pragma unroll
      for (int i = 0; i < 4; ++i) vns[w + 4 * i] = sqrtf(vvp[i]) + 1e-6f;
    }
    // per-token dot reduction
#pragma unroll
    for (int m = 1; m < 64; m <<= 1) {
      xx += __shfl_xor(xx, m);
#pragma unroll
      for (int e = 0; e < 16; ++e) dot[e] += __shfl_xor(dot[e], m);
    }
    __syncthreads();  // vns visible to all waves
    if (valid && lane == 0) {
      const float inv_sd = 1.0f / sqrtf((float)d);
      const float xnorm = sqrtf(xx) + 1e-6f;
      float s[16];
#pragma unroll
      for (int e = 0; e < 16; ++e)
        s[e] = (e < E) ? dot[e] / (xnorm * vns[e]) * inv_sd : -1e30f;
      int e0 = 0; float s0 = s[0];
#pragma unroll
      for (int e = 1; e < 16; ++e) if (s[e] > s0) { s0 = s[e]; e0 = e; }
      int e1 = (e0 == 0) ? 1 : 0; float s1 = s[e1];
#pragma unroll
      for (int e = 0; e < 16; ++e) if (e != e0 && s[e] > s1) { s1 = s[e]; e1 = e; }
      const int k = has_topk ? *topk_ptr : 2;
      float w0 = 1.f, w1 = 0.f;
      if (k >= 2) {
        const float ex = expf(s1 - s0);  // s0 >= s1 -> stable
        w0 = 1.f / (1.f + ex);
        w1 = ex / (1.f + ex);
      } else {
        e1 = e0;
      }
      Route rt;
      rt.e0 = e0; rt.e1 = e1;
      rt.c0 = w0 * ldf(alphas, e0, nAl) / (float)r;
      rt.c1 = w1 * ldf(alphas, e1, nAl) / (float)r;
      g_route[t] = rt;
    }
    return;
  }
  b -= Rblk;

  if (b < nWblk) {  // W -> g_wb
    const long long cap = (long long)MAX_DOUT * MAX_K;
    const long long stride = (long long)nWblk * 1024;
    for (long long i4 = ((long long)b * 256 + tid) * 4; i4 < nW; i4 += stride) {
      if (i4 + 4 <= nW && i4 + 4 <= cap) {
        const float4 v = *(const float4*)(W + i4);
        ushort4 o; o.x = f2b(v.x); o.y = f2b(v.y); o.z = f2b(v.z); o.w = f2b(v.w);
        *(ushort4*)&g_wb[i4] = o;
      } else {
        for (long long j = i4; j < nW && j < cap; ++j) g_wb[j] = f2b(W[j]);
      }
    }
    return;
  }
  b -= nWblk;
  if (b < nAblk) {  // A -> g_ab
    const long long cap = (long long)MAX_ER * MAX_K;
    const long long stride = (long long)nAblk * 1024;
    for (long long i4 = ((long long)b * 256 + tid) * 4; i4 < nA; i4 += stride) {
      if (i4 + 4 <= nA && i4 + 4 <= cap) {
        const float4 v = *(const float4*)(A + i4);
        ushort4 o; o.x = f2b(v.x); o.y = f2b(v.y); o.z = f2b(v.z); o.w = f2b(v.w);
        *(ushort4*)&g_ab[i4] = o;
      } else {
        for (long long j = i4; j < nA && j < cap; ++j) g_ab[j] = f2b(A[j]);
      }
    }
    return;
  }
  b -= nAblk;
  if (b < w2blk) {  // B -> g_w2 permuted
    const int gid = b * 256 + tid;
    if (gid >= d_out * E) return;
    const int o = gid / E, e = gid % E;
    const long long src = ((long long)e * d_out + o) * r;
    const long long dst = (long long)o * Er + (long long)e * r;
    if (r == 16 && src + 16 <= nB) {
      short8 lo, hi;
#pragma unroll
      for (int j = 0; j < 8; ++j) lo[j] = (short)f2b(Bw[src + j]);
#pragma unroll
      for (int j = 0; j < 8; ++j) hi[j] = (short)f2b(Bw[src + 8 + j]);
      *(short8*)&g_w2[dst] = lo;
      *(short8*)&g_w2[dst + 8] = hi;
    } else {
      for (int j = 0; j < r; ++j) g_w2[dst + j] = f2b(ldf(Bw, src + j, nB));
    }
  }
}

// ---------------- Legacy router (fallback; exact f32, self-contained) ----------------
__global__ __launch_bounds__(256) void router_cvtx(
    const float* __restrict__ x, long long nX,
    const float* __restrict__ gate_v, long long nG,
    const float* __restrict__ alphas, long long nAl,
    const int* __restrict__ topk_ptr, int has_topk,
    int T, int d, int r, int E) {
  const int wave = threadIdx.x >> 6, lane = threadIdx.x & 63;
  const int t = blockIdx.x * 4 + wave;
  if (t >= T || t >= MAX_T) return;
  float xx = 0.f, dot[16], vv[16];
#pragma unroll
  for (int e = 0; e < 16; ++e) { dot[e] = 0.f; vv[e] = 0.f; }
  const long long xbase = (long long)t * d;
  const int dvec = ((d & 3) == 0) ? d : 0;
  for (int i = lane * 4; i < dvec; i += 256) {
    const float4 xv = *(const float4*)(x + xbase + i);
    xx += xv.x * xv.x + xv.y * xv.y + xv.z * xv.z + xv.w * xv.w;
    ushort4 ob; ob.x = f2b(xv.x); ob.y = f2b(xv.y); ob.z = f2b(xv.z); ob.w = f2b(xv.w);
    *(ushort4*)&g_xb[xbase + i] = ob;
#pragma unroll
    for (int e = 0; e < 16; ++e) {
      if (e < E) {
        const float4 g = *(const float4*)(gate_v + (long long)e * d + i);
        dot[e] += xv.x * g.x + xv.y * g.y + xv.z * g.z + xv.w * g.w;
        vv[e] += g.x * g.x + g.y * g.y + g.z * g.z + g.w * g.w;
      }
    }
  }
  for (int i = dvec + lane; i < d; i += 64) {
    const float xv = ldf(x, xbase + i, nX);
    g_xb[xbase + i] = f2b(xv);
    xx += xv * xv;
#pragma unroll
    for (int e = 0; e < 16; ++e) {
      if (e < E) {
        const float g = ldf(gate_v, (long long)e * d + i, nG);
        dot[e] += xv * g;
        vv[e] += g * g;
      }
    }
  }
#pragma unroll
  for (int m = 1; m < 64; m <<= 1) {
    xx += __shfl_xor(xx, m);
#pragma unroll
    for (int e = 0; e < 16; ++e) {
      dot[e] += __shfl_xor(dot[e], m);
      vv[e] += __shfl_xor(vv[e], m);
    }
  }
  const float inv_sd = 1.0f / sqrtf((float)d);
  const float xnorm = sqrtf(xx) + 1e-6f;
  float s[16];
#pragma unroll
  for (int e = 0; e < 16; ++e)
    s[e] = (e < E) ? dot[e] / (xnorm * (sqrtf(vv[e]) + 1e-6f)) * inv_sd : -1e30f;
  int e0 = 0; float s0 = s[0];
#pragma unroll
  for (int e = 1; e < 16; ++e) if (s[e] > s0) { s0 = s[e]; e0 = e; }
  int e1 = (e0 == 0) ? 1 : 0; float s1 = s[e1];
#pragma unroll
  for (int e = 0; e < 16; ++e) if (e != e0 && s[e] > s1) { s1 = s[e]; e1 = e; }
  const int k = has_topk ? *topk_ptr : 2;
  float w0 = 1.f, w1 = 0.f;
  if (k >= 2) {
    const float ex = expf(s1 - s0);
    w0 = 1.f / (1.f + ex);
    w1 = ex / (1.f + ex);
  } else {
    e1 = e0;
  }
  if (lane == 0) {
    Route rt;
    rt.e0 = e0; rt.e1 = e1;
    rt.c0 = w0 * ldf(alphas, e0, nAl) / (float)r;
    rt.c1 = w1 * ldf(alphas, e1, nAl) / (float)r;
    g_route[t] = rt;
  }
}

// ================= Legacy 128^2 GEMM path (fallback) =================
#define BM 128
#define BN 128
#define BK 32

__global__ __launch_bounds__(256) void gemm_main(
    const float* __restrict__ bias, long long nBias,
    float* __restrict__ Out, long long nOut,
    int K, int d_out, int Er, int T) {
  __shared__ __align__(16) u16 As[BM * BK];
  __shared__ __align__(16) u16 Bs[BN * BK];
  const int tid = threadIdx.x;
  const int w = tid >> 6, lane = tid & 63;
  const int Mb = blockIdx.y * BM;
  const int Nb = blockIdx.x * BN;
  const int wm = w >> 1, wn = w & 1;
  const int chunk0 = w * 2;
  const int srow = lane >> 2;
  const int kb = (lane & 3) * 8;

  floatx4 acc[4][4];
#pragma unroll
  for (int mt = 0; mt < 4; ++mt)
#pragma unroll
    for (int nt = 0; nt < 4; ++nt) acc[mt][nt] = (floatx4){0.f, 0.f, 0.f, 0.f};

  for (int k0 = 0; k0 < K; k0 += BK) {
#pragma unroll
    for (int c = 0; c < 2; ++c) {
      const int row = (chunk0 + c) * 16 + srow;
      async_cp16(g_xb + (size_t)(Mb + row) * K + (k0 + kb), (char*)As + (chunk0 + c) * 1024);
    }
#pragma unroll
    for (int c = 0; c < 2; ++c) {
      const int row = (chunk0 + c) * 16 + srow;
      const int col = Nb + row;
      const u16* g = (col >= d_out) ? g_ab + (size_t)(col - d_out) * K + (k0 + kb)
                                    : g_wb + (size_t)col * K + (k0 + kb);
      async_cp16(g, (char*)Bs + (chunk0 + c) * 1024);
    }
    __syncthreads();
    short8 a[4], b[4];
#pragma unroll
    for (int mt = 0; mt < 4; ++mt)
      a[mt] = *(const short8*)&As[(wm * 64 + mt * 16 + (lane & 15)) * BK + (lane >> 4) * 8];
#pragma unroll
    for (int nt = 0; nt < 4; ++nt)
      b[nt] = *(const short8*)&Bs[(wn * 64 + nt * 16 + (lane & 15)) * BK + (lane >> 4) * 8];
#pragma unroll
    for (int mt = 0; mt < 4; ++mt)
#pragma unroll
      for (int nt = 0; nt < 4; ++nt)
        acc[mt][nt] = __builtin_amdgcn_mfma_f32_16x16x32_bf16(a[mt], b[nt], acc[mt][nt], 0, 0, 0);
    __syncthreads();
  }

  const int colb = Nb + wn * 64 + (lane & 15);
  const int rowb = Mb + wm * 64 + (lane >> 4) * 4;
#pragma unroll
  for (int nt = 0; nt < 4; ++nt) {
    const int col = colb + nt * 16;
    const bool isOut = (col < d_out);
    const float bv = isOut ? ldf(bias, col, nBias) : 0.f;
#pragma unroll
    for (int mt = 0; mt < 4; ++mt) {
      const int row = rowb + mt * 16;
#pragma unroll
      for (int i = 0; i < 4; ++i) {
        const int rr = row + i;
        if (rr >= T) continue;
        if (isOut) {
          const long long idx = (long long)rr * d_out + col;
          if (idx < nOut) Out[idx] = acc[mt][nt][i] + bv;
        } else {
          const int mc = col - d_out;
          if (mc < Er) g_mid[(long long)rr * Er + mc] = acc[mt][nt][i];
        }
      }
    }
  }
}

__global__ __launch_bounds__(256) void build_mw(int T, int r, int Er, int E) {
  const int t = blockIdx.x;
  if (t >= T) return;
  const Route rt = g_route[t];
  for (int j = threadIdx.x; j < Er; j += 256) {
    const int e = (r == 16) ? (j >> 4) : (j / r);
    float wgt = 0.f;
    if (e == rt.e0) wgt = rt.c0;
    else if (e == rt.e1) wgt = rt.c1;
    g_mw[(long long)t * Er + j] = f2b(wgt * g_mid[(long long)t * Er + j]);
  }
}

__global__ __launch_bounds__(256) void gemm_lora(
    float* __restrict__ Out, long long nOut, int Kc, int d_out, int T) {
  __shared__ __align__(16) u16 As[BM * BK];
  __shared__ __align__(16) u16 Bs[BN * BK];
  const int tid = threadIdx.x;
  const int w = tid >> 6, lane = tid & 63;
  const int Mb = blockIdx.y * BM;
  const int Nb = blockIdx.x * BN;
  const int wm = w >> 1, wn = w & 1;
  const int chunk0 = w * 2;
  const int srow = lane >> 2;
  const int kb = (lane & 3) * 8;

  floatx4 acc[4][4];
#pragma unroll
  for (int mt = 0; mt < 4; ++mt)
#pragma unroll
    for (int nt = 0; nt < 4; ++nt) acc[mt][nt] = (floatx4){0.f, 0.f, 0.f, 0.f};

  for (int k0 = 0; k0 < Kc; k0 += BK) {
#pragma unroll
    for (int c = 0; c < 2; ++c) {
      const int row = (chunk0 + c) * 16 + srow;
      async_cp16(g_mw + (size_t)(Mb + row) * Kc + (k0 + kb), (char*)As + (chunk0 + c) * 1024);
      async_cp16(g_w2 + (size_t)(Nb + row) * Kc + (k0 + kb), (char*)Bs + (chunk0 + c) * 1024);
    }
    __syncthreads();
    short8 a[4], b[4];
#pragma unroll
    for (int mt = 0; mt < 4; ++mt)
      a[mt] = *(const short8*)&As[(wm * 64 + mt * 16 + (lane & 15)) * BK + (lane >> 4) * 8];
#pragma unroll
    for (int nt = 0; nt < 4; ++nt)
      b[nt] = *(const short8*)&Bs[(wn * 64 + nt * 16 + (lane & 15)) * BK + (lane >> 4) * 8];
#pragma unroll
    for (int mt = 0; mt < 4; ++mt)
#pragma unroll
      for (int nt = 0; nt < 4; ++nt)
        acc[mt][nt] = __builtin_amdgcn_mfma_f32_16x16x32_bf16(a[mt], b[nt], acc[mt][nt], 0, 0, 0);
    __syncthreads();
  }

  const int colb = Nb + wn * 64 + (lane & 15);
  const int rowb = Mb + wm * 64 + (lane >> 4) * 4;
#pragma unroll
  for (int nt = 0; nt < 4; ++nt) {
    const int col = colb + nt * 16;
#pragma unroll
    for (int mt = 0; mt < 4; ++mt) {
      const int row = rowb + mt * 16;
#pragma unroll
      for (int i = 0; i < 4; ++i) {
        const int rr = row + i;
        if (rr >= T) continue;
        const long long idx = (long long)rr * d_out + col;
        if (idx < nOut) Out[idx] += acc[mt][nt][i];
      }
    }
  }
}

// ================= Fast path =================

// ---- mid GEMM, 128x64 tile -> 256 blocks (full CU coverage) ----
__global__ __launch_bounds__(256) void gemm_mid64(int K, int Er, int T, int r) {
  __shared__ __align__(16) u16 As[128 * 32];
  __shared__ __align__(16) u16 Bs[64 * 32];
  const int tid = threadIdx.x;
  const int w = tid >> 6, lane = tid & 63;
  int lin = blockIdx.y * gridDim.x + blockIdx.x;
  const int nwg = gridDim.x * gridDim.y;
  if ((nwg & 7) == 0) { const int cpx = nwg >> 3; lin = (lin & 7) * cpx + (lin >> 3); }
  const int Mb = (lin / gridDim.x) * 128;
  const int Nb = (lin % gridDim.x) * 64;
  const int wm = w >> 1, wn = w & 1;
  const int srow = lane >> 2;
  const int kb = (lane & 3) * 8;
  const int lane15 = lane & 15, laneHi = lane >> 4;

  floatx4 acc[4][2];
#pragma unroll
  for (int mt = 0; mt < 4; ++mt)
#pragma unroll
    for (int nt = 0; nt < 2; ++nt) acc[mt][nt] = (floatx4){0.f, 0.f, 0.f, 0.f};

  for (int k0 = 0; k0 < K; k0 += 32) {
#pragma unroll
    for (int c = 0; c < 2; ++c) {
      const int ci = w * 2 + c;
      async_cp16(g_xb + (size_t)(Mb + ci * 16 + srow) * K + (k0 + kb), (char*)As + ci * 1024);
    }
    async_cp16(g_ab + (size_t)(Nb + w * 16 + srow) * K + (k0 + kb), (char*)Bs + w * 1024);
    __syncthreads();
    short8 a[4], b[2];
#pragma unroll
    for (int mt = 0; mt < 4; ++mt)
      a[mt] = *(const short8*)&As[(wm * 64 + mt * 16 + lane15) * 32 + laneHi * 8];
#pragma unroll
    for (int nt = 0; nt < 2; ++nt)
      b[nt] = *(const short8*)&Bs[(wn * 32 + nt * 16 + lane15) * 32 + laneHi * 8];
#pragma unroll
    for (int mt = 0; mt < 4; ++mt)
#pragma unroll
      for (int nt = 0; nt < 2; ++nt)
        acc[mt][nt] = __builtin_amdgcn_mfma_f32_16x16x32_bf16(a[mt], b[nt], acc[mt][nt], 0, 0, 0);
    __syncthreads();
  }

  const int colb = Nb + wn * 32 + lane15;
  const int rowb = Mb + wm * 64 + laneHi * 4;
#pragma unroll
  for (int mt = 0; mt < 4; ++mt) {
#pragma unroll
    for (int i = 0; i < 4; ++i) {
      const int rr = rowb + mt * 16 + i;
      if (rr >= T) continue;
      const Route rt = g_route[rr];
#pragma unroll
      for (int nt = 0; nt < 2; ++nt) {
        const int col = colb + nt * 16;
        if (col >= Er) continue;
        const int e = (r == 16) ? (col >> 4) : (col / r);
        float wgt = 0.f;
        if (e == rt.e0) wgt = rt.c0;
        else if (e == rt.e1) wgt = rt.c1;
        g_mw[(long long)rr * Er + col] = f2b(wgt * acc[mt][nt][i]);
      }
    }
  }
}

// ---- 256^2 8-phase main GEMM: Out = [X|Mw] @ [W|W2]^T + bias ----
DEV void stage_ht(int tsched, int half, int isB, int NT, int Mb, int Nb,
                  int Kxb, int Er, char* smem, int w, int lane) {
  int t = (tsched < NT) ? tsched : (NT - 1);   // clamp SOURCE only
  const int k0 = t << 6;
  const u16* src; int stride, col0;
  if (k0 < Kxb) { src = isB ? g_wb : g_xb; stride = Kxb; col0 = k0; }
  else          { src = isB ? g_w2 : g_mw; stride = Er;  col0 = k0 - Kxb; }
  const int rbase = (isB ? Nb : Mb) + (half << 7);
  char* dst = smem + (tsched & 1) * 65536 + isB * 32768 + half * 16384 + (w * 2) * 1024;
  const int row = w * 16 + (lane >> 3);
  const int cs = (((lane & 7) ^ (lane >> 3)) << 3);  // inverse swizzle, elems
#pragma unroll
  for (int c = 0; c < 2; ++c) {
    async_cp16(src + (size_t)(rbase + row + c * 8) * stride + col0 + cs, dst + c * 1024);
  }
}

__global__ __launch_bounds__(512, 2) void gemm_main8(
    const float* __restrict__ bias, long long nBias,
    float* __restrict__ Out, long long nOut,
    int Kxb, int d_out, int Er, int T) {
  __shared__ __align__(16) char smem[131072];
  const int tid = threadIdx.x;
  const int w = tid >> 6, lane = tid & 63;
  const int wm = w >> 2, wn = w & 3;
  const int lane15 = lane & 15, laneHi = lane >> 4, lane7 = lane & 7;
  const int NT = (Kxb + Er) >> 6;

  int lin = blockIdx.y * gridDim.x + blockIdx.x;
  const int nwg = gridDim.x * gridDim.y;
  if ((nwg & 7) == 0) { const int cpx = nwg >> 3; lin = (lin & 7) * cpx + (lin >> 3); }
  const int Nb = (lin % gridDim.x) * 256;
  const int Mb = (lin / gridDim.x) * 256;

  floatx4 acc[8][4];
#pragma unroll
  for (int m = 0; m < 8; ++m)
#pragma unroll
    for (int n = 0; n < 4; ++n) acc[m][n] = (floatx4){0.f, 0.f, 0.f, 0.f};

  // prologue: A0(0) A1(0) B0(0) B1(0) B0(1) B1(1); keep B(1) in flight.
  stage_ht(0, 0, 0, NT, Mb, Nb, Kxb, Er, smem, w, lane);
  stage_ht(0, 1, 0, NT, Mb, Nb, Kxb, Er, smem, w, lane);
  stage_ht(0, 0, 1, NT, Mb, Nb, Kxb, Er, smem, w, lane);
  stage_ht(0, 1, 1, NT, Mb, Nb, Kxb, Er, smem, w, lane);
  stage_ht(1, 0, 1, NT, Mb, Nb, Kxb, Er, smem, w, lane);
  stage_ht(1, 1, 1, NT, Mb, Nb, Kxb, Er, smem, w, lane);
  asm volatile("s_waitcnt vmcnt(4)" ::: "memory");
  __builtin_amdgcn_s_barrier();
  asm volatile("" ::: "memory");

  const int xorw = lane7 << 4;
  short8 a[2][2], b[4][2];

  for (int t = 0; t < NT; ++t) {
    const int sbase = (t & 1) * 65536;
    const char* Ab = smem + sbase;
    const char* Bb = smem + sbase + 32768;
#pragma unroll
    for (int q = 0; q < 4; ++q) {
      if (q == 0) {
#pragma unroll
        for (int n = 0; n < 4; ++n)
#pragma unroll
          for (int kk = 0; kk < 2; ++kk)
            b[n][kk] = *(const short8*)(Bb + (wn * 64 + n * 16 + lane15) * 128 +
                                        ((kk * 64 + laneHi * 16) ^ xorw));
      }
#pragma unroll
      for (int mm = 0; mm < 2; ++mm)
#pragma unroll
        for (int kk = 0; kk < 2; ++kk)
          a[mm][kk] = *(const short8*)(Ab + (wm * 128 + (2 * q + mm) * 16 + lane15) * 128 +
                                       ((kk * 64 + laneHi * 16) ^ xorw));
      if (q < 2) stage_ht(t + 1, q, 0, NT, Mb, Nb, Kxb, Er, smem, w, lane);
      else       stage_ht(t + 2, q - 2, 1, NT, Mb, Nb, Kxb, Er, smem, w, lane);
      if (q == 3) asm volatile("s_waitcnt vmcnt(4)" ::: "memory");
      __builtin_amdgcn_s_barrier();
      asm volatile("" ::: "memory");
      asm volatile("s_waitcnt lgkmcnt(0)" ::: "memory");
      __builtin_amdgcn_s_setprio(1);
#pragma unroll
      for (int kk = 0; kk < 2; ++kk)
#pragma unroll
        for (int mm = 0; mm < 2; ++mm)
#pragma unroll
          for (int n = 0; n < 4; ++n)
            acc[2 * q + mm][n] =
                __builtin_amdgcn_mfma_f32_16x16x32_bf16(a[mm][kk], b[n][kk], acc[2 * q + mm][n], 0, 0, 0);
      __builtin_amdgcn_s_setprio(0);
      __builtin_amdgcn_s_barrier();
      asm volatile("" ::: "memory");
    }
  }
  asm volatile("s_waitcnt vmcnt(0)" ::: "memory");  // drain tail stages before exit

  // Direct-store epilogue (R11 version; LDS round-trip regressed in R12).
  const int colb = Nb + wn * 64 + lane15;
  const int rowb = Mb + wm * 128 + laneHi * 4;
#pragma unroll
  for (int n = 0; n < 4; ++n) {
    const int col = colb + n * 16;
    const float bv = ldf(bias, col, nBias);
#pragma unroll
    for (int m = 0; m < 8; ++m) {
#pragma unroll
      for (int i = 0; i < 4; ++i) {
        const int row = rowb + m * 16 + i;
        const long long idx = (long long)row * d_out + col;
        if (row < T && idx < nOut) Out[idx] = acc[m][n][i] + bv;
      }
    }
  }
}

extern "C" void kernel_launch(void* const* d_in, const int* in_sizes, int n_in,
                              void* d_out, int out_size, void* d_ws, size_t ws_size,
                              hipStream_t stream) {
  if (n_in < 7 || !d_out) return;
  const float* x    = (const float*)d_in[0];
  const float* W    = (const float*)d_in[1];
  const float* bias = (const float*)d_in[2];
  const float* A    = (const float*)d_in[3];
  const float* B    = (const float*)d_in[4];
  const float* gv   = (const float*)d_in[5];
  const float* al   = (const float*)d_in[6];
  const int has_topk = (n_in > 7 && in_sizes[7] >= 1) ? 1 : 0;
  const int* topk = has_topk ? (const int*)d_in[7] : nullptr;
  float* out = (float*)d_out;

  const long long nX = in_sizes[0], nW = in_sizes[1], nBias = in_sizes[2];
  const long long nA = in_sizes[3], nB = in_sizes[4], nG = in_sizes[5], nAl = in_sizes[6];
  const long long nOut = (long long)out_size;

  const int E = in_sizes[6] > 0 ? in_sizes[6] : 1;               // 16
  int d = (int)(nG / E); if (d < 1) d = 1;                       // 2048
  const int d_out_dim = in_sizes[2] > 0 ? in_sizes[2] : 1;       // 2048
  int T = (int)(nX / d);                                         // 8192
  int r = (int)(nA / ((long long)E * d)); if (r < 1) r = 1;      // 16
  const int Er = E * r;                                          // 256
  if (T < 1) return;
  if (T > MAX_T) T = MAX_T;
  if (d > MAX_K || d_out_dim > MAX_DOUT || Er > MAX_ER) return;

  const bool fastr = (d % 256 == 0) && (E <= 16);
  const int Rblk = fastr ? (T + 3) / 4 : 0;
  const int nWblk = 2048, nAblk = 256;
  const int w2blk = (d_out_dim * E + 255) / 256;

  // fused router + prep (one dispatch; prep blocks backfill CUs)
  router_prep<<<Rblk + nWblk + nAblk + w2blk, 256, 0, stream>>>(
      x, nX, gv, nG, al, nAl, topk, has_topk,
      W, nW, A, nA, B, nB,
      T, d, d_out_dim, r, E, Er, Rblk, nWblk, nAblk, w2blk);
  if (!fastr)
    router_cvtx<<<(T + 3) / 4, 256, 0, stream>>>(x, nX, gv, nG, al, nAl, topk, has_topk, T, d, r, E);

  const bool fast = (T % 256 == 0) && (d_out_dim % 256 == 0) && (d % 64 == 0) &&
                    (Er % 64 == 0) && (((d + Er) >> 6) >= 2) && (Er >= 64);
  if (fast) {
    dim3 gmid(Er / 64, T / 128);
    gemm_mid64<<<gmid, 256, 0, stream>>>(d, Er, T, r);
    dim3 gmain(d_out_dim / 256, T / 256);
    gemm_main8<<<gmain, 512, 0, stream>>>(bias, nBias, out, nOut, d, d_out_dim, Er, T);
  } else {
    dim3 grid1((d_out_dim + Er + BN - 1) / BN, (T + BM - 1) / BM);
    gemm_main<<<grid1, 256, 0, stream>>>(bias, nBias, out, nOut, d, d_out_dim, Er, T);
    build_mw<<<T, 256, 0, stream>>>(T, r, Er, E);
    dim3 grid2((d_out_dim + BN - 1) / BN, (T + BM - 1) / BM);
    gemm_lora<<<grid2, 256, 0, stream>>>(out, nOut, Er, d_out_dim, T);
  }
}

// Round 11
// 287.063 us; speedup vs baseline: 1.0668x; 1.0668x over previous
//
#include <hip/hip_runtime.h>
#include <math.h>

// Round 15: R14's prep+router fusion REGRESSED non-main8 (~190->211us):
// 32KB LDS dbuf halved router co-residency (8->5 blocks/CU) and starved the
// prep blocks too -> reverted to R13's separate prep_all + router_lds (16KB,
// all 2048 blocks co-resident). New finding: gemm_mid64 had an 8-way LDS
// read conflict (64B rows) + 1 block/CU sync staging. New mid: BM64/BN64/
// BK64, 512 blocks (2/CU), T2 XOR swizzle both-sides. main8 frozen.

typedef unsigned short u16;
typedef __attribute__((ext_vector_type(8))) short short8;
typedef __attribute__((ext_vector_type(4))) float floatx4;

#define DEV __device__ __forceinline__

DEV u16 f2b(float f) { unsigned int u; __builtin_memcpy(&u, &f, 4); u += 0x7fffu + ((u >> 16) & 1u); return (u16)(u >> 16); }
DEV float ldf(const float* __restrict__ p, long long i, long long n) { if (i < 0 || i >= n) i = 0; return p[i]; }

DEV void async_cp16(const void* g, void* l) {
  __builtin_amdgcn_global_load_lds(
      (const __attribute__((address_space(1))) unsigned int*)g,
      (__attribute__((address_space(3))) unsigned int*)l, 16, 0, 0);
}

struct Route { int e0, e1; float c0, c1; };

#define MAX_T 8192
#define MAX_K 2048
#define MAX_DOUT 2048
#define MAX_ER 256

__device__ Route g_route[MAX_T];
__device__ float g_vnorm[16];                                 // ||gate_v[e]|| + eps
__device__ float g_mid[(size_t)MAX_T * MAX_ER];               // legacy path
__device__ __align__(16) u16 g_xb[(size_t)MAX_T * MAX_K];     // x bf16
__device__ __align__(16) u16 g_wb[(size_t)MAX_DOUT * MAX_K];  // base_W bf16
__device__ __align__(16) u16 g_ab[(size_t)MAX_ER * MAX_K];    // A bf16
__device__ __align__(16) u16 g_mw[(size_t)MAX_T * MAX_ER];    // weighted mid bf16
__device__ __align__(16) u16 g_w2[(size_t)MAX_DOUT * MAX_ER]; // B permuted bf16

// ---------------- Fused prep: cvt W, cvt A, build_w2, gate_norm ----------------
__global__ __launch_bounds__(256) void prep_all(
    const float* __restrict__ W, long long nW,
    const float* __restrict__ A, long long nA,
    const float* __restrict__ Bw, long long nB,
    const float* __restrict__ gv, long long nG,
    int d, int d_out, int r, int E, int Er,
    int nWblk, int nAblk, int w2blk) {
  int b = blockIdx.x;
  const int tid = threadIdx.x;
  if (b < nWblk) {  // W -> g_wb
    const long long cap = (long long)MAX_DOUT * MAX_K;
    const long long stride = (long long)nWblk * 1024;
    for (long long i4 = ((long long)b * 256 + tid) * 4; i4 < nW; i4 += stride) {
      if (i4 + 4 <= nW && i4 + 4 <= cap) {
        const float4 v = *(const float4*)(W + i4);
        ushort4 o; o.x = f2b(v.x); o.y = f2b(v.y); o.z = f2b(v.z); o.w = f2b(v.w);
        *(ushort4*)&g_wb[i4] = o;
      } else {
        for (long long j = i4; j < nW && j < cap; ++j) g_wb[j] = f2b(W[j]);
      }
    }
    return;
  }
  b -= nWblk;
  if (b < nAblk) {  // A -> g_ab
    const long long cap = (long long)MAX_ER * MAX_K;
    const long long stride = (long long)nAblk * 1024;
    for (long long i4 = ((long long)b * 256 + tid) * 4; i4 < nA; i4 += stride) {
      if (i4 + 4 <= nA && i4 + 4 <= cap) {
        const float4 v = *(const float4*)(A + i4);
        ushort4 o; o.x = f2b(v.x); o.y = f2b(v.y); o.z = f2b(v.z); o.w = f2b(v.w);
        *(ushort4*)&g_ab[i4] = o;
      } else {
        for (long long j = i4; j < nA && j < cap; ++j) g_ab[j] = f2b(A[j]);
      }
    }
    return;
  }
  b -= nAblk;
  if (b < w2blk) {  // B -> g_w2 permuted
    const int gid = b * 256 + tid;
    if (gid >= d_out * E) return;
    const int o = gid / E, e = gid % E;
    const long long src = ((long long)e * d_out + o) * r;
    const long long dst = (long long)o * Er + (long long)e * r;
    if (r == 16 && src + 16 <= nB) {
      short8 lo, hi;
#pragma unroll
      for (int j = 0; j < 8; ++j) lo[j] = (short)f2b(Bw[src + j]);
#pragma unroll
      for (int j = 0; j < 8; ++j) hi[j] = (short)f2b(Bw[src + 8 + j]);
      *(short8*)&g_w2[dst] = lo;
      *(short8*)&g_w2[dst + 8] = hi;
    } else {
      for (int j = 0; j < r; ++j) g_w2[dst + j] = f2b(ldf(Bw, src + j, nB));
    }
    return;
  }
  b -= w2blk;
  // gate norms: block b = expert e (lanes 0-63 only)
  if (b < E && b < 16 && tid < 64) {
    float vv = 0.f;
    const float* gp = gv + (long long)b * d;
    for (int k = tid * 4; k + 4 <= d; k += 256) {
      const float4 g = *(const float4*)(gp + k);
      vv += g.x * g.x + g.y * g.y + g.z * g.z + g.w * g.w;
    }
#pragma unroll
    for (int m = 1; m < 64; m <<= 1) vv += __shfl_xor(vv, m);
    if (tid == 0) g_vnorm[b] = sqrtf(vv) + 1e-6f;
  }
}

// ---------------- Legacy router (fallback; exact f32) ----------------
__global__ __launch_bounds__(256) void router_cvtx(
    const float* __restrict__ x, long long nX,
    const float* __restrict__ gate_v, long long nG,
    const float* __restrict__ alphas, long long nAl,
    const int* __restrict__ topk_ptr, int has_topk,
    int T, int d, int r, int E) {
  const int wave = threadIdx.x >> 6, lane = threadIdx.x & 63;
  const int t = blockIdx.x * 4 + wave;
  if (t >= T || t >= MAX_T) return;
  float xx = 0.f, dot[16], vv[16];
#pragma unroll
  for (int e = 0; e < 16; ++e) { dot[e] = 0.f; vv[e] = 0.f; }
  const long long xbase = (long long)t * d;
  const int dvec = ((d & 3) == 0) ? d : 0;
  for (int i = lane * 4; i < dvec; i += 256) {
    const float4 xv = *(const float4*)(x + xbase + i);
    xx += xv.x * xv.x + xv.y * xv.y + xv.z * xv.z + xv.w * xv.w;
    ushort4 ob; ob.x = f2b(xv.x); ob.y = f2b(xv.y); ob.z = f2b(xv.z); ob.w = f2b(xv.w);
    *(ushort4*)&g_xb[xbase + i] = ob;
#pragma unroll
    for (int e = 0; e < 16; ++e) {
      if (e < E) {
        const float4 g = *(const float4*)(gate_v + (long long)e * d + i);
        dot[e] += xv.x * g.x + xv.y * g.y + xv.z * g.z + xv.w * g.w;
        vv[e] += g.x * g.x + g.y * g.y + g.z * g.z + g.w * g.w;
      }
    }
  }
  for (int i = dvec + lane; i < d; i += 64) {
    const float xv = ldf(x, xbase + i, nX);
    g_xb[xbase + i] = f2b(xv);
    xx += xv * xv;
#pragma unroll
    for (int e = 0; e < 16; ++e) {
      if (e < E) {
        const float g = ldf(gate_v, (long long)e * d + i, nG);
        dot[e] += xv * g;
        vv[e] += g * g;
      }
    }
  }
#pragma unroll
  for (int m = 1; m < 64; m <<= 1) {
    xx += __shfl_xor(xx, m);
#pragma unroll
    for (int e = 0; e < 16; ++e) {
      dot[e] += __shfl_xor(dot[e], m);
      vv[e] += __shfl_xor(vv[e], m);
    }
  }
  const float inv_sd = 1.0f / sqrtf((float)d);
  const float xnorm = sqrtf(xx) + 1e-6f;
  float s[16];
#pragma unroll
  for (int e = 0; e < 16; ++e)
    s[e] = (e < E) ? dot[e] / (xnorm * (sqrtf(vv[e]) + 1e-6f)) * inv_sd : -1e30f;
  int e0 = 0; float s0 = s[0];
#pragma unroll
  for (int e = 1; e < 16; ++e) if (s[e] > s0) { s0 = s[e]; e0 = e; }
  int e1 = (e0 == 0) ? 1 : 0; float s1 = s[e1];
#pragma unroll
  for (int e = 0; e < 16; ++e) if (e != e0 && s[e] > s1) { s1 = s[e]; e1 = e; }
  const int k = has_topk ? *topk_ptr : 2;
  float w0 = 1.f, w1 = 0.f;
  if (k >= 2) {
    const float ex = expf(s1 - s0);
    w0 = 1.f / (1.f + ex);
    w1 = ex / (1.f + ex);
  } else {
    e1 = e0;
  }
  if (lane == 0) {
    Route rt;
    rt.e0 = e0; rt.e1 = e1;
    rt.c0 = w0 * ldf(alphas, e0, nAl) / (float)r;
    rt.c1 = w1 * ldf(alphas, e1, nAl) / (float)r;
    g_route[t] = rt;
  }
}

// ---------------- Fast router: LDS-staged gate chunks, 1 token/wave ----------------
// 16KB LDS -> all 2048 blocks co-resident (8 blocks/CU). Proven in R11/R13.
__global__ __launch_bounds__(256) void router_lds(
    const float* __restrict__ x, long long nX,
    const float* __restrict__ gate_v, long long nG,
    const float* __restrict__ alphas, long long nAl,
    const int* __restrict__ topk_ptr, int has_topk,
    int T, int d, int r, int E) {
  __shared__ __align__(16) float gls[4096];  // 16 experts x 256 floats = 16KB
  const int tid = threadIdx.x;
  const int w = tid >> 6, lane = tid & 63;
  const int t = blockIdx.x * 4 + w;
  const bool valid = (t < T && t < MAX_T);
  const long long xbase = (long long)t * d;

  float dot[16], xx = 0.f;
#pragma unroll
  for (int e = 0; e < 16; ++e) dot[e] = 0.f;

  for (int k0 = 0; k0 < d; k0 += 256) {
    __syncthreads();  // previous chunk fully consumed before overwrite
#pragma unroll
    for (int i = 0; i < 4; ++i) {
      const int f = tid * 4 + i * 1024;  // flat [e][kk]
      const int e = f >> 8, kk = f & 255;
      float4 g = (float4){0.f, 0.f, 0.f, 0.f};
      if (e < E) g = *(const float4*)(gate_v + (long long)e * d + k0 + kk);
      *(float4*)&gls[f] = g;
    }
    __syncthreads();
    float4 xv = (float4){0.f, 0.f, 0.f, 0.f};
    if (valid) {
      xv = *(const float4*)(x + xbase + k0 + lane * 4);
      ushort4 ob; ob.x = f2b(xv.x); ob.y = f2b(xv.y); ob.z = f2b(xv.z); ob.w = f2b(xv.w);
      *(ushort4*)&g_xb[xbase + k0 + lane * 4] = ob;
    }
    xx += xv.x * xv.x + xv.y * xv.y + xv.z * xv.z + xv.w * xv.w;
#pragma unroll
    for (int e = 0; e < 16; ++e) {
      if (e < E) {
        const float4 g = *(const float4*)&gls[e * 256 + lane * 4];
        dot[e] += xv.x * g.x + xv.y * g.y + xv.z * g.z + xv.w * g.w;
      }
    }
  }
#pragma unroll
  for (int m = 1; m < 64; m <<= 1) {
    xx += __shfl_xor(xx, m);
#pragma unroll
    for (int e = 0; e < 16; ++e) dot[e] += __shfl_xor(dot[e], m);
  }
  if (valid && lane == 0) {
    const float inv_sd = 1.0f / sqrtf((float)d);
    const float xnorm = sqrtf(xx) + 1e-6f;
    float s[16];
#pragma unroll
    for (int e = 0; e < 16; ++e)
      s[e] = (e < E) ? dot[e] / (xnorm * g_vnorm[e]) * inv_sd : -1e30f;
    int e0 = 0; float s0 = s[0];
#pragma unroll
    for (int e = 1; e < 16; ++e) if (s[e] > s0) { s0 = s[e]; e0 = e; }
    int e1 = (e0 == 0) ? 1 : 0; float s1 = s[e1];
#pragma unroll
    for (int e = 0; e < 16; ++e) if (e != e0 && s[e] > s1) { s1 = s[e]; e1 = e; }
    const int k = has_topk ? *topk_ptr : 2;
    float w0 = 1.f, w1 = 0.f;
    if (k >= 2) {
      const float ex = expf(s1 - s0);  // s0 >= s1 -> stable
      w0 = 1.f / (1.f + ex);
      w1 = ex / (1.f + ex);
    } else {
      e1 = e0;
    }
    Route rt;
    rt.e0 = e0; rt.e1 = e1;
    rt.c0 = w0 * ldf(alphas, e0, nAl) / (float)r;
    rt.c1 = w1 * ldf(alphas, e1, nAl) / (float)r;
    g_route[t] = rt;
  }
}

// ================= Legacy 128^2 GEMM path (fallback) =================
#define BM 128
#define BN 128
#define BK 32

__global__ __launch_bounds__(256) void gemm_main(
    const float* __restrict__ bias, long long nBias,
    float* __restrict__ Out, long long nOut,
    int K, int d_out, int Er, int T) {
  __shared__ __align__(16) u16 As[BM * BK];
  __shared__ __align__(16) u16 Bs[BN * BK];
  const int tid = threadIdx.x;
  const int w = tid >> 6, lane = tid & 63;
  const int Mb = blockIdx.y * BM;
  const int Nb = blockIdx.x * BN;
  const int wm = w >> 1, wn = w & 1;
  const int chunk0 = w * 2;
  const int srow = lane >> 2;
  const int kb = (lane & 3) * 8;

  floatx4 acc[4][4];
#pragma unroll
  for (int mt = 0; mt < 4; ++mt)
#pragma unroll
    for (int nt = 0; nt < 4; ++nt) acc[mt][nt] = (floatx4){0.f, 0.f, 0.f, 0.f};

  for (int k0 = 0; k0 < K; k0 += BK) {
#pragma unroll
    for (int c = 0; c < 2; ++c) {
      const int row = (chunk0 + c) * 16 + srow;
      async_cp16(g_xb + (size_t)(Mb + row) * K + (k0 + kb), (char*)As + (chunk0 + c) * 1024);
    }
#pragma unroll
    for (int c = 0; c < 2; ++c) {
      const int row = (chunk0 + c) * 16 + srow;
      const int col = Nb + row;
      const u16* g = (col >= d_out) ? g_ab + (size_t)(col - d_out) * K + (k0 + kb)
                                    : g_wb + (size_t)col * K + (k0 + kb);
      async_cp16(g, (char*)Bs + (chunk0 + c) * 1024);
    }
    __syncthreads();
    short8 a[4], b[4];
#pragma unroll
    for (int mt = 0; mt < 4; ++mt)
      a[mt] = *(const short8*)&As[(wm * 64 + mt * 16 + (lane & 15)) * BK + (lane >> 4) * 8];
#pragma unroll
    for (int nt = 0; nt < 4; ++nt)
      b[nt] = *(const short8*)&Bs[(wn * 64 + nt * 16 + (lane & 15)) * BK + (lane >> 4) * 8];
#pragma unroll
    for (int mt = 0; mt < 4; ++mt)
#pragma unroll
      for (int nt = 0; nt < 4; ++nt)
        acc[mt][nt] = __builtin_amdgcn_mfma_f32_16x16x32_bf16(a[mt], b[nt], acc[mt][nt], 0, 0, 0);
    __syncthreads();
  }

  const int colb = Nb + wn * 64 + (lane & 15);
  const int rowb = Mb + wm * 64 + (lane >> 4) * 4;
#pragma unroll
  for (int nt = 0; nt < 4; ++nt) {
    const int col = colb + nt * 16;
    const bool isOut = (col < d_out);
    const float bv = isOut ? ldf(bias, col, nBias) : 0.f;
#pragma unroll
    for (int mt = 0; mt < 4; ++mt) {
      const int row = rowb + mt * 16;
#pragma unroll
      for (int i = 0; i < 4; ++i) {
        const int rr = row + i;
        if (rr >= T) continue;
        if (isOut) {
          const long long idx = (long long)rr * d_out + col;
          if (idx < nOut) Out[idx] = acc[mt][nt][i] + bv;
        } else {
          const int mc = col - d_out;
          if (mc < Er) g_mid[(long long)rr * Er + mc] = acc[mt][nt][i];
        }
      }
    }
  }
}

__global__ __launch_bounds__(256) void build_mw(int T, int r, int Er, int E) {
  const int t = blockIdx.x;
  if (t >= T) return;
  const Route rt = g_route[t];
  for (int j = threadIdx.x; j < Er; j += 256) {
    const int e = (r == 16) ? (j >> 4) : (j / r);
    float wgt = 0.f;
    if (e == rt.e0) wgt = rt.c0;
    else if (e == rt.e1) wgt = rt.c1;
    g_mw[(long long)t * Er + j] = f2b(wgt * g_mid[(long long)t * Er + j]);
  }
}

__global__ __launch_bounds__(256) void gemm_lora(
    float* __restrict__ Out, long long nOut, int Kc, int d_out, int T) {
  __shared__ __align__(16) u16 As[BM * BK];
  __shared__ __align__(16) u16 Bs[BN * BK];
  const int tid = threadIdx.x;
  const int w = tid >> 6, lane = tid & 63;
  const int Mb = blockIdx.y * BM;
  const int Nb = blockIdx.x * BN;
  const int wm = w >> 1, wn = w & 1;
  const int chunk0 = w * 2;
  const int srow = lane >> 2;
  const int kb = (lane & 3) * 8;

  floatx4 acc[4][4];
#pragma unroll
  for (int mt = 0; mt < 4; ++mt)
#pragma unroll
    for (int nt = 0; nt < 4; ++nt) acc[mt][nt] = (floatx4){0.f, 0.f, 0.f, 0.f};

  for (int k0 = 0; k0 < Kc; k0 += BK) {
#pragma unroll
    for (int c = 0; c < 2; ++c) {
      const int row = (chunk0 + c) * 16 + srow;
      async_cp16(g_mw + (size_t)(Mb + row) * Kc + (k0 + kb), (char*)As + (chunk0 + c) * 1024);
      async_cp16(g_w2 + (size_t)(Nb + row) * Kc + (k0 + kb), (char*)Bs + (chunk0 + c) * 1024);
    }
    __syncthreads();
    short8 a[4], b[4];
#pragma unroll
    for (int mt = 0; mt < 4; ++mt)
      a[mt] = *(const short8*)&As[(wm * 64 + mt * 16 + (lane & 15)) * BK + (lane >> 4) * 8];
#pragma unroll
    for (int nt = 0; nt < 4; ++nt)
      b[nt] = *(const short8*)&Bs[(wn * 64 + nt * 16 + (lane & 15)) * BK + (lane >> 4) * 8];
#pragma unroll
    for (int mt = 0; mt < 4; ++mt)
#pragma unroll
      for (int nt = 0; nt < 4; ++nt)
        acc[mt][nt] = __builtin_amdgcn_mfma_f32_16x16x32_bf16(a[mt], b[nt], acc[mt][nt], 0, 0, 0);
    __syncthreads();
  }

  const int colb = Nb + wn * 64 + (lane & 15);
  const int rowb = Mb + wm * 64 + (lane >> 4) * 4;
#pragma unroll
  for (int nt = 0; nt < 4; ++nt) {
    const int col = colb + nt * 16;
#pragma unroll
    for (int mt = 0; mt < 4; ++mt) {
      const int row = rowb + mt * 16;
#pragma unroll
      for (int i = 0; i < 4; ++i) {
        const int rr = row + i;
        if (rr >= T) continue;
        const long long idx = (long long)rr * d_out + col;
        if (idx < nOut) Out[idx] += acc[mt][nt][i];
      }
    }
  }
}

// ================= Fast path =================

// ---- mid GEMM, 64x64x64 tile -> 512 blocks (2/CU), XOR-swizzled LDS ----
// Staging: 8 chunks/operand (1KB = 8 rows x 128B); wave w stages A,B chunks
// 2w,2w+1. Global src pre-swizzled col ((lane&7)^(lane>>3))*8 elems; read
// side XORs byte with (row&7)<<4 -> 2-way (free) instead of 8-way conflict.
__global__ __launch_bounds__(256) void gemm_mid64(int K, int Er, int T, int r) {
  __shared__ __align__(16) u16 As[64 * 64];
  __shared__ __align__(16) u16 Bs[64 * 64];
  const int tid = threadIdx.x;
  const int w = tid >> 6, lane = tid & 63;
  int lin = blockIdx.y * gridDim.x + blockIdx.x;
  const int nwg = gridDim.x * gridDim.y;
  if ((nwg & 7) == 0) { const int cpx = nwg >> 3; lin = (lin & 7) * cpx + (lin >> 3); }
  const int Mb = (lin / gridDim.x) * 64;
  const int Nb = (lin % gridDim.x) * 64;
  const int wm = w >> 1, wn = w & 1;  // 2x2 waves, 32x32 out each
  const int lane15 = lane & 15, laneHi = lane >> 4;
  const int srow = lane >> 3;                         // 0..7 within chunk
  const int scol = (((lane & 7) ^ (lane >> 3)) << 3); // pre-swizzled elems

  floatx4 acc[2][2];
#pragma unroll
  for (int mt = 0; mt < 2; ++mt)
#pragma unroll
    for (int nt = 0; nt < 2; ++nt) acc[mt][nt] = (floatx4){0.f, 0.f, 0.f, 0.f};

  for (int k0 = 0; k0 < K; k0 += 64) {
#pragma unroll
    for (int c = 0; c < 2; ++c) {
      const int ci = w * 2 + c;
      async_cp16(g_xb + (size_t)(Mb + ci * 8 + srow) * K + k0 + scol, (char*)As + ci * 1024);
      async_cp16(g_ab + (size_t)(Nb + ci * 8 + srow) * K + k0 + scol, (char*)Bs + ci * 1024);
    }
    __syncthreads();
    short8 a[2][2], b[2][2];
#pragma unroll
    for (int mm = 0; mm < 2; ++mm)
#pragma unroll
      for (int kk = 0; kk < 2; ++kk) {
        const int ar = wm * 32 + mm * 16 + lane15;
        const int br = wn * 32 + mm * 16 + lane15;
        const int kb = (kk * 64 + laneHi * 16);
        a[mm][kk] = *(const short8*)((const char*)As + ar * 128 + (kb ^ ((ar & 7) << 4)));
        b[mm][kk] = *(const short8*)((const char*)Bs + br * 128 + (kb ^ ((br & 7) << 4)));
      }
#pragma unroll
    for (int kk = 0; kk < 2; ++kk)
#pragma unroll
      for (int mm = 0; mm < 2; ++mm)
#pragma unroll
        for (int nn = 0; nn < 2; ++nn)
          acc[mm][nn] = __builtin_amdgcn_mfma_f32_16x16x32_bf16(a[mm][kk], b[nn][kk], acc[mm][nn], 0, 0, 0);
    __syncthreads();
  }

  // weighted bf16 epilogue -> g_mw
  const int colb = Nb + wn * 32 + lane15;
  const int rowb = Mb + wm * 32 + laneHi * 4;
#pragma unroll
  for (int mm = 0; mm < 2; ++mm) {
#pragma unroll
    for (int i = 0; i < 4; ++i) {
      const int rr = rowb + mm * 16 + i;
      if (rr >= T) continue;
      const Route rt = g_route[rr];
#pragma unroll
      for (int nn = 0; nn < 2; ++nn) {
        const int col = colb + nn * 16;
        if (col >= Er) continue;
        const int e = (r == 16) ? (col >> 4) : (col / r);
        float wgt = 0.f;
        if (e == rt.e0) wgt = rt.c0;
        else if (e == rt.e1) wgt = rt.c1;
        g_mw[(long long)rr * Er + col] = f2b(wgt * acc[mm][nn][i]);
      }
    }
  }
}

// ---- 256^2 8-phase main GEMM: Out = [X|Mw] @ [W|W2]^T + bias (FROZEN) ----
DEV void stage_ht(int tsched, int half, int isB, int NT, int Mb, int Nb,
                  int Kxb, int Er, char* smem, int w, int lane) {
  int t = (tsched < NT) ? tsched : (NT - 1);   // clamp SOURCE only
  const int k0 = t << 6;
  const u16* src; int stride, col0;
  if (k0 < Kxb) { src = isB ? g_wb : g_xb; stride = Kxb; col0 = k0; }
  else          { src = isB ? g_w2 : g_mw; stride = Er;  col0 = k0 - Kxb; }
  const int rbase = (isB ? Nb : Mb) + (half << 7);
  char* dst = smem + (tsched & 1) * 65536 + isB * 32768 + half * 16384 + (w * 2) * 1024;
  const int row = w * 16 + (lane >> 3);
  const int cs = (((lane & 7) ^ (lane >> 3)) << 3);  // inverse swizzle, elems
#pragma unroll
  for (int c = 0; c < 2; ++c) {
    async_cp16(src + (size_t)(rbase + row + c * 8) * stride + col0 + cs, dst + c * 1024);
  }
}

__global__ __launch_bounds__(512, 2) void gemm_main8(
    const float* __restrict__ bias, long long nBias,
    float* __restrict__ Out, long long nOut,
    int Kxb, int d_out, int Er, int T) {
  __shared__ __align__(16) char smem[131072];
  const int tid = threadIdx.x;
  const int w = tid >> 6, lane = tid & 63;
  const int wm = w >> 2, wn = w & 3;
  const int lane15 = lane & 15, laneHi = lane >> 4, lane7 = lane & 7;
  const int NT = (Kxb + Er) >> 6;

  int lin = blockIdx.y * gridDim.x + blockIdx.x;
  const int nwg = gridDim.x * gridDim.y;
  if ((nwg & 7) == 0) { const int cpx = nwg >> 3; lin = (lin & 7) * cpx + (lin >> 3); }
  const int Nb = (lin % gridDim.x) * 256;
  const int Mb = (lin / gridDim.x) * 256;

  floatx4 acc[8][4];
#pragma unroll
  for (int m = 0; m < 8; ++m)
#pragma unroll
    for (int n = 0; n < 4; ++n) acc[m][n] = (floatx4){0.f, 0.f, 0.f, 0.f};

  // prologue: A0(0) A1(0) B0(0) B1(0) B0(1) B1(1); keep B(1) in flight.
  stage_ht(0, 0, 0, NT, Mb, Nb, Kxb, Er, smem, w, lane);
  stage_ht(0, 1, 0, NT, Mb, Nb, Kxb, Er, smem, w, lane);
  stage_ht(0, 0, 1, NT, Mb, Nb, Kxb, Er, smem, w, lane);
  stage_ht(0, 1, 1, NT, Mb, Nb, Kxb, Er, smem, w, lane);
  stage_ht(1, 0, 1, NT, Mb, Nb, Kxb, Er, smem, w, lane);
  stage_ht(1, 1, 1, NT, Mb, Nb, Kxb, Er, smem, w, lane);
  asm volatile("s_waitcnt vmcnt(4)" ::: "memory");
  __builtin_amdgcn_s_barrier();
  asm volatile("" ::: "memory");

  const int xorw = lane7 << 4;
  short8 a[2][2], b[4][2];

  for (int t = 0; t < NT; ++t) {
    const int sbase = (t & 1) * 65536;
    const char* Ab = smem + sbase;
    const char* Bb = smem + sbase + 32768;
#pragma unroll
    for (int q = 0; q < 4; ++q) {
      if (q == 0) {
#pragma unroll
        for (int n = 0; n < 4; ++n)
#pragma unroll
          for (int kk = 0; kk < 2; ++kk)
            b[n][kk] = *(const short8*)(Bb + (wn * 64 + n * 16 + lane15) * 128 +
                                        ((kk * 64 + laneHi * 16) ^ xorw));
      }
#pragma unroll
      for (int mm = 0; mm < 2; ++mm)
#pragma unroll
        for (int kk = 0; kk < 2; ++kk)
          a[mm][kk] = *(const short8*)(Ab + (wm * 128 + (2 * q + mm) * 16 + lane15) * 128 +
                                       ((kk * 64 + laneHi * 16) ^ xorw));
      if (q < 2) stage_ht(t + 1, q, 0, NT, Mb, Nb, Kxb, Er, smem, w, lane);
      else       stage_ht(t + 2, q - 2, 1, NT, Mb, Nb, Kxb, Er, smem, w, lane);
      if (q == 3) asm volatile("s_waitcnt vmcnt(4)" ::: "memory");
      __builtin_amdgcn_s_barrier();
      asm volatile("" ::: "memory");
      asm volatile("s_waitcnt lgkmcnt(0)" ::: "memory");
      __builtin_amdgcn_s_setprio(1);
#pragma unroll
      for (int kk = 0; kk < 2; ++kk)
#pragma unroll
        for (int mm = 0; mm < 2; ++mm)
#pragma unroll
          for (int n = 0; n < 4; ++n)
            acc[2 * q + mm][n] =
                __builtin_amdgcn_mfma_f32_16x16x32_bf16(a[mm][kk], b[n][kk], acc[2 * q + mm][n], 0, 0, 0);
      __builtin_amdgcn_s_setprio(0);
      __builtin_amdgcn_s_barrier();
      asm volatile("" ::: "memory");
    }
  }
  asm volatile("s_waitcnt vmcnt(0)" ::: "memory");  // drain tail stages before exit

  // Direct-store epilogue (R11 version; LDS round-trip regressed in R12).
  const int colb = Nb + wn * 64 + lane15;
  const int rowb = Mb + wm * 128 + laneHi * 4;
#pragma unroll
  for (int n = 0; n < 4; ++n) {
    const int col = colb + n * 16;
    const float bv = ldf(bias, col, nBias);
#pragma unroll
    for (int m = 0; m < 8; ++m) {
#pragma unroll
      for (int i = 0; i < 4; ++i) {
        const int row = rowb + m * 16 + i;
        const long long idx = (long long)row * d_out + col;
        if (row < T && idx < nOut) Out[idx] = acc[m][n][i] + bv;
      }
    }
  }
}

extern "C" void kernel_launch(void* const* d_in, const int* in_sizes, int n_in,
                              void* d_out, int out_size, void* d_ws, size_t ws_size,
                              hipStream_t stream) {
  if (n_in < 7 || !d_out) return;
  const float* x    = (const float*)d_in[0];
  const float* W    = (const float*)d_in[1];
  const float* bias = (const float*)d_in[2];
  const float* A    = (const float*)d_in[3];
  const float* B    = (const float*)d_in[4];
  const float* gv   = (const float*)d_in[5];
  const float* al   = (const float*)d_in[6];
  const int has_topk = (n_in > 7 && in_sizes[7] >= 1) ? 1 : 0;
  const int* topk = has_topk ? (const int*)d_in[7] : nullptr;
  float* out = (float*)d_out;

  const long long nX = in_sizes[0], nW = in_sizes[1], nBias = in_sizes[2];
  const long long nA = in_sizes[3], nB = in_sizes[4], nG = in_sizes[5], nAl = in_sizes[6];
  const long long nOut = (long long)out_size;

  const int E = in_sizes[6] > 0 ? in_sizes[6] : 1;               // 16
  int d = (int)(nG / E); if (d < 1) d = 1;                       // 2048
  const int d_out_dim = in_sizes[2] > 0 ? in_sizes[2] : 1;       // 2048
  int T = (int)(nX / d);                                         // 8192
  int r = (int)(nA / ((long long)E * d)); if (r < 1) r = 1;      // 16
  const int Er = E * r;                                          // 256
  if (T < 1) return;
  if (T > MAX_T) T = MAX_T;
  if (d > MAX_K || d_out_dim > MAX_DOUT || Er > MAX_ER) return;

  // fused prep (cvt W, cvt A, build_w2, gate norms) — one dispatch
  const int nWblk = 2048, nAblk = 256;
  const int w2blk = (d_out_dim * E + 255) / 256;
  prep_all<<<nWblk + nAblk + w2blk + E, 256, 0, stream>>>(
      W, nW, A, nA, B, nB, gv, nG, d, d_out_dim, r, E, Er, nWblk, nAblk, w2blk);

  const bool fastr = (d % 256 == 0) && (E <= 16);
  if (fastr)
    router_lds<<<(T + 3) / 4, 256, 0, stream>>>(x, nX, gv, nG, al, nAl, topk, has_topk, T, d, r, E);
  else
    router_cvtx<<<(T + 3) / 4, 256, 0, stream>>>(x, nX, gv, nG, al, nAl, topk, has_topk, T, d, r, E);

  const bool fast = (T % 256 == 0) && (d_out_dim % 256 == 0) && (d % 64 == 0) &&
                    (Er % 64 == 0) && (((d + Er) >> 6) >= 2) && (Er >= 64);
  if (fast) {
    dim3 gmid(Er / 64, T / 64);
    gemm_mid64<<<gmid, 256, 0, stream>>>(d, Er, T, r);
    dim3 gmain(d_out_dim / 256, T / 256);
    gemm_main8<<<gmain, 512, 0, stream>>>(bias, nBias, out, nOut, d, d_out_dim, Er, T);
  } else {
    dim3 grid1((d_out_dim + Er + BN - 1) / BN, (T + BM - 1) / BM);
    gemm_main<<<grid1, 256, 0, stream>>>(bias, nBias, out, nOut, d, d_out_dim, Er, T);
    build_mw<<<T, 256, 0, stream>>>(T, r, Er, E);
    dim3 grid2((d_out_dim + BN - 1) / BN, (T + BM - 1) / BM);
    gemm_lora<<<grid2, 256, 0, stream>>>(out, nOut, Er, d_out_dim, T);
  }
}